// Round 1
// baseline (912.749 us; speedup 1.0000x reference)
//
#include <hip/hip_runtime.h>
#include <stdint.h>

#define NROWS 65536
#define IDIM 2048

typedef __attribute__((ext_vector_type(4))) float v4f;
typedef __attribute__((ext_vector_type(8))) short v8s;

__device__ __forceinline__ unsigned short f2bf(float f) {
  unsigned int u = __float_as_uint(f);
  u += 0x7fffu + ((u >> 16) & 1u);          // round-to-nearest-even
  return (unsigned short)(u >> 16);
}

struct Expert {
  const unsigned short* w1t;   // [HN][2048] bf16 (row n, contiguous in k)
  const float* b1;
  const unsigned short* w2t;   // [HN/2][HN] bf16
  const float* b2;
  const float* w3;             // [HN/2]
  const float* b3;             // [1]
  const int* idx;              // this expert's row-index list
  const int* count;
};
struct Quad { Expert e[4]; };

// ---------------- prep kernel 1: bucket rows by label ----------------
__global__ void build_lists(const int* __restrict__ labels, float* __restrict__ out,
                            int* __restrict__ counts, int* __restrict__ idx, int n)
{
  __shared__ int lcnt[4];
  __shared__ int lbase[4];
  const int t = threadIdx.x;
  if (t < 4) lcnt[t] = 0;
  __syncthreads();
  const int i = blockIdx.x * blockDim.x + t;
  int lbl = -1, pos = 0;
  if (i < n) {
    lbl = labels[i];
    if (lbl >= 0 && lbl <= 3) {
      pos = atomicAdd(&lcnt[lbl], 1);
    } else {
      out[i] = 0.f;   // rows with unknown label output 0 (d_out is poisoned)
      lbl = -1;
    }
  }
  __syncthreads();
  if (t < 4) lbase[t] = atomicAdd(&counts[t], lcnt[t]);
  __syncthreads();
  if (lbl >= 0) idx[lbl * NROWS + lbase[lbl] + pos] = i;
}

// ---------------- prep kernel 2: transpose + fp32->bf16 weights (all 4 experts) ----------------
struct ConvArgs {
  const float* W1[4]; const float* W2[4];
  unsigned short* w1t[4]; unsigned short* w2t[4];
  int HN[4];
};

__global__ void conv_all(ConvArgs c)
{
  const int e = blockIdx.y;
  const int HN = c.HN[e];
  const int HN2 = HN >> 1;
  const int n1 = IDIM * HN;
  const int total = n1 + HN * HN2;
  const int i = blockIdx.x * blockDim.x + threadIdx.x;
  if (i >= total) return;
  if (i < n1) {
    int nn = i / IDIM, k = i - nn * IDIM;
    c.w1t[e][i] = f2bf(c.W1[e][k * HN + nn]);        // w1t[n][k] = W1[k][n]
  } else {
    int j = i - n1;
    int nn = j / HN, k = j - nn * HN;
    c.w2t[e][j] = f2bf(c.W2[e][k * HN2 + nn]);       // w2t[n][k] = W2[k][n]
  }
}

// ---------------- main fused kernel ----------------
// Barrier-free K-loop: A-fragments loaded straight from gathered x rows
// (fp32->bf16 in-register), B-fragments straight from w1t (bf16, L2-resident:
// 1.5 MiB total vs 4 MiB/XCD). h1 lives in wave-private LDS (no barrier);
// W2T staged once (single __syncthreads per block, placed after the K-loop so
// no wave ever waits at startup). LDS = 52224 B -> 3 blocks/CU = 12 waves/CU.
template<int HN>
__device__ __forceinline__ void moe_body(const float* __restrict__ x, float* __restrict__ out,
                                         const Expert E, char* smem)
{
  constexpr int HN2 = HN / 2;
  constexpr int TM = 128;
  constexpr int H1W = HN + 8;
  constexpr int NF1 = HN / 16;
  constexpr int NF2 = HN2 / 16;

  unsigned short* sH1 = (unsigned short*)smem;       // [TM][H1W]  (wave-private 32-row slices)
  unsigned short* sW2 = sH1 + TM * H1W;              // [HN2][H1W] (shared, staged once)

  const int cnt = *E.count;
  const int tile0 = blockIdx.x * TM;
  if (tile0 >= cnt) return;
  const int rv = min(TM, cnt - tile0);

  const int t    = threadIdx.x;
  const int lane = t & 63;
  const int l15  = lane & 15;
  const int quad = lane >> 4;
  const int m0w  = (t >> 6) * 32;   // wave's first row of the 128-row tile

  // stage W2T -> LDS (shared); the barrier that publishes it comes after the K-loop
  {
    constexpr int CH = HN2 * HN / 8;     // 16B chunks (256 or 1024)
    #pragma unroll
    for (int i = 0; i < CH / 256; ++i) {
      const int cc = i * 256 + t;
      const int nn = cc / (HN / 8), kc = (cc % (HN / 8)) * 8;
      *(v8s*)&sW2[nn * H1W + kc] = *(const v8s*)(E.w2t + nn * HN + kc);
    }
  }

  // per-lane row ids for this wave's two A-fragment rows
  const int r0 = m0w + l15;
  const int r1 = m0w + 16 + l15;
  const int rid0 = E.idx[tile0 + (r0 < rv ? r0 : 0)];
  const int rid1 = E.idx[tile0 + (r1 < rv ? r1 : 0)];
  const float* p0 = x + (size_t)rid0 * IDIM + quad * 8;
  const float* p1 = x + (size_t)rid1 * IDIM + quad * 8;
  const unsigned short* bp = E.w1t + (size_t)l15 * IDIM + quad * 8;

  v4f acc[2][NF1];
  #pragma unroll
  for (int mi = 0; mi < 2; ++mi)
    #pragma unroll
    for (int ni = 0; ni < NF1; ++ni)
      acc[mi][ni] = (v4f){0.f, 0.f, 0.f, 0.f};

  // 1-deep software pipeline on the A (HBM) loads
  v4f c00 = *(const v4f*)(p0);
  v4f c01 = *(const v4f*)(p0 + 4);
  v4f c10 = *(const v4f*)(p1);
  v4f c11 = *(const v4f*)(p1 + 4);

  #pragma unroll 1
  for (int k0 = 0; k0 < IDIM; k0 += 32) {
    v4f n00 = c00, n01 = c01, n10 = c10, n11 = c11;
    const int kn = k0 + 32;
    if (kn < IDIM) {
      n00 = *(const v4f*)(p0 + kn); n01 = *(const v4f*)(p0 + kn + 4);
      n10 = *(const v4f*)(p1 + kn); n11 = *(const v4f*)(p1 + kn + 4);
    }
    v8s b[NF1];
    #pragma unroll
    for (int ni = 0; ni < NF1; ++ni)
      b[ni] = *(const v8s*)(bp + (size_t)ni * 16 * IDIM + k0);

    v8s a0, a1;
    a0[0]=(short)f2bf(c00[0]); a0[1]=(short)f2bf(c00[1]); a0[2]=(short)f2bf(c00[2]); a0[3]=(short)f2bf(c00[3]);
    a0[4]=(short)f2bf(c01[0]); a0[5]=(short)f2bf(c01[1]); a0[6]=(short)f2bf(c01[2]); a0[7]=(short)f2bf(c01[3]);
    a1[0]=(short)f2bf(c10[0]); a1[1]=(short)f2bf(c10[1]); a1[2]=(short)f2bf(c10[2]); a1[3]=(short)f2bf(c10[3]);
    a1[4]=(short)f2bf(c11[0]); a1[5]=(short)f2bf(c11[1]); a1[6]=(short)f2bf(c11[2]); a1[7]=(short)f2bf(c11[3]);

    #pragma unroll
    for (int ni = 0; ni < NF1; ++ni) {
      acc[0][ni] = __builtin_amdgcn_mfma_f32_16x16x32_bf16(a0, b[ni], acc[0][ni], 0, 0, 0);
      acc[1][ni] = __builtin_amdgcn_mfma_f32_16x16x32_bf16(a1, b[ni], acc[1][ni], 0, 0, 0);
    }
    c00 = n00; c01 = n01; c10 = n10; c11 = n11;
  }

  // epilogue 1: h1 = relu(acc + b1) -> wave-private LDS slice, bf16
  unsigned short* myH1 = sH1 + m0w * H1W;
  #pragma unroll
  for (int mi = 0; mi < 2; ++mi) {
    #pragma unroll
    for (int ni = 0; ni < NF1; ++ni) {
      const int col = ni * 16 + l15;
      const float b1v = E.b1[col];
      #pragma unroll
      for (int r = 0; r < 4; ++r) {
        const int row = mi * 16 + quad * 4 + r;
        myH1[row * H1W + col] = f2bf(fmaxf(acc[mi][ni][r] + b1v, 0.f));
      }
    }
  }

  __syncthreads();   // publishes sW2 (written pre-loop) to all waves

  // layer 2: h2 = relu(h1 @ W2 + b2), MFMA, K = HN; h2 stays in f32 registers
  v4f acc2[2][NF2];
  #pragma unroll
  for (int mi = 0; mi < 2; ++mi)
    #pragma unroll
    for (int ni = 0; ni < NF2; ++ni)
      acc2[mi][ni] = (v4f){0.f, 0.f, 0.f, 0.f};
  #pragma unroll
  for (int ks = 0; ks < HN / 32; ++ks) {
    v8s a20 = *(const v8s*)&myH1[l15 * H1W + ks * 32 + quad * 8];
    v8s a21 = *(const v8s*)&myH1[(16 + l15) * H1W + ks * 32 + quad * 8];
    #pragma unroll
    for (int ni = 0; ni < NF2; ++ni) {
      v8s b2 = *(const v8s*)&sW2[(ni * 16 + l15) * H1W + ks * 32 + quad * 8];
      acc2[0][ni] = __builtin_amdgcn_mfma_f32_16x16x32_bf16(a20, b2, acc2[0][ni], 0, 0, 0);
      acc2[1][ni] = __builtin_amdgcn_mfma_f32_16x16x32_bf16(a21, b2, acc2[1][ni], 0, 0, 0);
    }
  }

  // layer 3: out = h2 @ W3 + b3, in-register shuffle reduce over the 16 acc columns
  float w3v[NF2], b2v[NF2];
  #pragma unroll
  for (int ni = 0; ni < NF2; ++ni) {
    const int c = ni * 16 + l15;
    w3v[ni] = E.w3[c];
    b2v[ni] = E.b2[c];
  }
  const float b3v = E.b3[0];
  #pragma unroll
  for (int mi = 0; mi < 2; ++mi) {
    #pragma unroll
    for (int r = 0; r < 4; ++r) {
      float s = 0.f;
      #pragma unroll
      for (int ni = 0; ni < NF2; ++ni)
        s = fmaf(fmaxf(acc2[mi][ni][r] + b2v[ni], 0.f), w3v[ni], s);
      s += __shfl_xor(s, 1);
      s += __shfl_xor(s, 2);
      s += __shfl_xor(s, 4);
      s += __shfl_xor(s, 8);
      if (l15 == 0) {
        const int row = m0w + mi * 16 + quad * 4 + r;
        if (row < rv) out[E.idx[tile0 + row]] = s + b3v;
      }
    }
  }
}

__global__ __launch_bounds__(256, 3)
void moe_main(const float* __restrict__ x, float* __restrict__ out, Quad q)
{
  // max LDS: HN=128 -> (128+64)*136*2 = 52224 B -> 3 blocks/CU
  __shared__ __align__(16) char smem[52224];
  const int e = blockIdx.y;
  if (e < 2) moe_body<64>(x, out, q.e[e], smem);
  else       moe_body<128>(x, out, q.e[e], smem);
}

// ---------------- host ----------------
extern "C" void kernel_launch(void* const* d_in, const int* in_sizes, int n_in,
                              void* d_out, int out_size, void* d_ws, size_t ws_size,
                              hipStream_t stream)
{
  const float* x   = (const float*)d_in[0];
  const int* labels = (const int*)d_in[1];
  float* out = (float*)d_out;

  char* ws = (char*)d_ws;
  int* counts = (int*)ws;                       // 16 B
  int* idx = (int*)(ws + 256);                  // 4 * 65536 ints = 1 MiB
  static const int HNs[4] = {64, 64, 128, 128};
  unsigned short* w1t[4];
  unsigned short* w2t[4];
  size_t off = 256 + (size_t)4 * NROWS * 4;
  for (int e = 0; e < 4; ++e) { w1t[e] = (unsigned short*)(ws + off); off += (size_t)IDIM * HNs[e] * 2; }
  for (int e = 0; e < 4; ++e) { w2t[e] = (unsigned short*)(ws + off); off += (size_t)HNs[e] * (HNs[e] / 2) * 2; }

  hipMemsetAsync(counts, 0, 4 * sizeof(int), stream);
  build_lists<<<dim3(NROWS / 256), dim3(256), 0, stream>>>(labels, out, counts, idx, NROWS);

  ConvArgs ca;
  for (int e = 0; e < 4; ++e) {
    ca.W1[e] = (const float*)d_in[2 + 6 * e + 0];
    ca.W2[e] = (const float*)d_in[2 + 6 * e + 2];
    ca.w1t[e] = w1t[e];
    ca.w2t[e] = w2t[e];
    ca.HN[e] = HNs[e];
  }
  // max total = IDIM*128 + 128*64 = 270336 -> 1056 blocks of 256
  conv_all<<<dim3(1056, 4), dim3(256), 0, stream>>>(ca);

  Quad q;
  for (int e = 0; e < 4; ++e) {
    q.e[e].w1t = w1t[e];
    q.e[e].b1  = (const float*)d_in[2 + 6 * e + 1];
    q.e[e].w2t = w2t[e];
    q.e[e].b2  = (const float*)d_in[2 + 6 * e + 3];
    q.e[e].w3  = (const float*)d_in[2 + 6 * e + 4];
    q.e[e].b3  = (const float*)d_in[2 + 6 * e + 5];
    q.e[e].idx = idx + (size_t)e * NROWS;
    q.e[e].count = counts + e;
  }
  moe_main<<<dim3(NROWS / 128, 4), dim3(256), 0, stream>>>(x, out, q);
}

// Round 2
// 825.477 us; speedup vs baseline: 1.1057x; 1.1057x over previous
//
#include <hip/hip_runtime.h>
#include <stdint.h>

#define NROWS 65536
#define IDIM 2048

typedef __attribute__((ext_vector_type(4))) float v4f;
typedef __attribute__((ext_vector_type(8))) short v8s;

__device__ __forceinline__ unsigned short f2bf(float f) {
  unsigned int u = __float_as_uint(f);
  u += 0x7fffu + ((u >> 16) & 1u);          // round-to-nearest-even
  return (unsigned short)(u >> 16);
}

struct Expert {
  const unsigned short* w1t;   // [HN][2048] bf16 (row n, contiguous in k)
  const float* b1;
  const unsigned short* w2t;   // [HN/2][HN] bf16
  const float* b2;
  const float* w3;             // [HN/2]
  const float* b3;             // [1]
  const int* idx;              // this expert's row-index list
  const int* count;
};
struct Quad { Expert e[4]; };

// ---------------- prep kernel 1: bucket rows by label ----------------
__global__ void build_lists(const int* __restrict__ labels, float* __restrict__ out,
                            int* __restrict__ counts, int* __restrict__ idx, int n)
{
  __shared__ int lcnt[4];
  __shared__ int lbase[4];
  const int t = threadIdx.x;
  if (t < 4) lcnt[t] = 0;
  __syncthreads();
  const int i = blockIdx.x * blockDim.x + t;
  int lbl = -1, pos = 0;
  if (i < n) {
    lbl = labels[i];
    if (lbl >= 0 && lbl <= 3) {
      pos = atomicAdd(&lcnt[lbl], 1);
    } else {
      out[i] = 0.f;   // rows with unknown label output 0 (d_out is poisoned)
      lbl = -1;
    }
  }
  __syncthreads();
  if (t < 4) lbase[t] = atomicAdd(&counts[t], lcnt[t]);
  __syncthreads();
  if (lbl >= 0) idx[lbl * NROWS + lbase[lbl] + pos] = i;
}

// ---------------- prep kernel 2: transpose + fp32->bf16 weights (all 4 experts) ----------------
struct ConvArgs {
  const float* W1[4]; const float* W2[4];
  unsigned short* w1t[4]; unsigned short* w2t[4];
  int HN[4];
};

__global__ void conv_all(ConvArgs c)
{
  const int e = blockIdx.y;
  const int HN = c.HN[e];
  const int HN2 = HN >> 1;
  const int n1 = IDIM * HN;
  const int total = n1 + HN * HN2;
  const int i = blockIdx.x * blockDim.x + threadIdx.x;
  if (i >= total) return;
  if (i < n1) {
    int nn = i / IDIM, k = i - nn * IDIM;
    c.w1t[e][i] = f2bf(c.W1[e][k * HN + nn]);        // w1t[n][k] = W1[k][n]
  } else {
    int j = i - n1;
    int nn = j / HN, k = j - nn * HN;
    c.w2t[e][j] = f2bf(c.W2[e][k * HN2 + nn]);       // w2t[n][k] = W2[k][n]
  }
}

// ---------------- main fused kernel ----------------
// Round-0 structure (coalesced LDS staging of gathered A rows + L2-resident B),
// improved: TM=64 with 1 M-frag/wave (2x blocks -> ~12 waves/CU), double-buffered
// A+B staging with ONE barrier per K-step and issue-early/write-late loads (T14),
// wave-private h1, f32 h2 in registers, shuffle-reduce layer 3.
// LDS (HN=128): 2*64*40*2 + 2*128*40*2 + 64*136*2 = 48128 B -> 3 blocks/CU.
template<int HN>
__device__ __forceinline__ void moe_body(const float* __restrict__ x, float* __restrict__ out,
                                         const Expert E, char* smem)
{
  constexpr int HN2 = HN / 2;
  constexpr int TM  = 64;
  constexpr int BK  = 32;
  constexpr int AW  = BK + 8;     // 40: padded row stride, breaks bank alignment, keeps 16B align
  constexpr int H1W = HN + 8;
  constexpr int NF1 = HN / 16;
  constexpr int NF2 = HN2 / 16;
  constexpr int BCH = HN * BK / 8 / 256;   // v8s B-chunks per thread (2 for HN=128, 1 for 64)

  unsigned short* sA0 = (unsigned short*)smem;          // [TM][AW]
  unsigned short* sA1 = sA0 + TM * AW;
  unsigned short* sB0 = sA1 + TM * AW;                  // [HN][AW]
  unsigned short* sB1 = sB0 + HN * AW;
  unsigned short* sH1 = sB1 + HN * AW;                  // [TM][H1W] wave-private slices
  unsigned short* sW2 = (unsigned short*)smem;          // [HN2][H1W] aliases A/B after K-loop

  const int cnt = *E.count;
  const int tile0 = blockIdx.x * TM;
  if (tile0 >= cnt) return;
  const int rv = min(TM, cnt - tile0);

  const int t    = threadIdx.x;
  const int lane = t & 63;
  const int l15  = lane & 15;
  const int quad = lane >> 4;
  const int m0   = (t >> 6) * 16;    // wave's 16 rows of the 64-row tile

  // A staging assignment: thread t owns row ar, 8 cols at ac (32B of a 128B row)
  const int ar = t >> 2;             // 0..63
  const int ac = (t & 3) * 8;        // 0,8,16,24
  const int ridA = E.idx[tile0 + (ar < rv ? ar : 0)];
  const float* ap = x + (size_t)ridA * IDIM + ac;

  v4f acc[NF1];
  #pragma unroll
  for (int ni = 0; ni < NF1; ++ni) acc[ni] = (v4f){0.f, 0.f, 0.f, 0.f};

  // ---- staging helpers (inlined by hand via lambdas) ----
  auto stageA = [&](unsigned short* dA, int kk) {
    v4f va = *(const v4f*)(ap + kk);
    v4f vb = *(const v4f*)(ap + kk + 4);
    v8s pk;
    pk[0]=(short)f2bf(va[0]); pk[1]=(short)f2bf(va[1]); pk[2]=(short)f2bf(va[2]); pk[3]=(short)f2bf(va[3]);
    pk[4]=(short)f2bf(vb[0]); pk[5]=(short)f2bf(vb[1]); pk[6]=(short)f2bf(vb[2]); pk[7]=(short)f2bf(vb[3]);
    *(v8s*)&dA[ar * AW + ac] = pk;
  };
  auto stageB = [&](unsigned short* dB, int kk) {
    #pragma unroll
    for (int i = 0; i < BCH; ++i) {
      const int c = i * 256 + t;
      const int row = c >> 2, col8 = (c & 3) * 8;
      *(v8s*)&dB[row * AW + col8] = *(const v8s*)(E.w1t + (size_t)row * IDIM + kk + col8);
    }
  };
  auto compute = [&](const unsigned short* cA, const unsigned short* cB) {
    v8s a = *(const v8s*)&cA[(m0 + l15) * AW + quad * 8];
    #pragma unroll
    for (int ni = 0; ni < NF1; ++ni) {
      v8s b = *(const v8s*)&cB[(ni * 16 + l15) * AW + quad * 8];
      acc[ni] = __builtin_amdgcn_mfma_f32_16x16x32_bf16(a, b, acc[ni], 0, 0, 0);
    }
  };

  // prologue: stage k=0 into buf0
  stageA(sA0, 0);
  stageB(sB0, 0);
  __syncthreads();

  #pragma unroll 1
  for (int k0 = 0; k0 < IDIM; k0 += 2 * BK) {
    // step A: stage k0+BK into buf1 (loads issued before compute), compute buf0
    {
      v4f va = *(const v4f*)(ap + k0 + BK);
      v4f vb = *(const v4f*)(ap + k0 + BK + 4);
      v8s bg[BCH];
      #pragma unroll
      for (int i = 0; i < BCH; ++i) {
        const int c = i * 256 + t;
        const int row = c >> 2, col8 = (c & 3) * 8;
        bg[i] = *(const v8s*)(E.w1t + (size_t)row * IDIM + k0 + BK + col8);
      }
      compute(sA0, sB0);
      v8s pk;
      pk[0]=(short)f2bf(va[0]); pk[1]=(short)f2bf(va[1]); pk[2]=(short)f2bf(va[2]); pk[3]=(short)f2bf(va[3]);
      pk[4]=(short)f2bf(vb[0]); pk[5]=(short)f2bf(vb[1]); pk[6]=(short)f2bf(vb[2]); pk[7]=(short)f2bf(vb[3]);
      *(v8s*)&sA1[ar * AW + ac] = pk;
      #pragma unroll
      for (int i = 0; i < BCH; ++i) {
        const int c = i * 256 + t;
        const int row = c >> 2, col8 = (c & 3) * 8;
        *(v8s*)&sB1[row * AW + col8] = bg[i];
      }
      __syncthreads();
    }
    // step B: stage k0+2*BK into buf0 (unless past end), compute buf1
    {
      const int kn = k0 + 2 * BK;
      v4f va, vb; v8s bg[BCH];
      const bool more = (kn < IDIM);
      if (more) {
        va = *(const v4f*)(ap + kn);
        vb = *(const v4f*)(ap + kn + 4);
        #pragma unroll
        for (int i = 0; i < BCH; ++i) {
          const int c = i * 256 + t;
          const int row = c >> 2, col8 = (c & 3) * 8;
          bg[i] = *(const v8s*)(E.w1t + (size_t)row * IDIM + kn + col8);
        }
      }
      compute(sA1, sB1);
      if (more) {
        v8s pk;
        pk[0]=(short)f2bf(va[0]); pk[1]=(short)f2bf(va[1]); pk[2]=(short)f2bf(va[2]); pk[3]=(short)f2bf(va[3]);
        pk[4]=(short)f2bf(vb[0]); pk[5]=(short)f2bf(vb[1]); pk[6]=(short)f2bf(vb[2]); pk[7]=(short)f2bf(vb[3]);
        *(v8s*)&sA0[ar * AW + ac] = pk;
        #pragma unroll
        for (int i = 0; i < BCH; ++i) {
          const int c = i * 256 + t;
          const int row = c >> 2, col8 = (c & 3) * 8;
          *(v8s*)&sB0[row * AW + col8] = bg[i];
        }
      }
      __syncthreads();   // last iteration: doubles as the pre-W2T barrier
    }
  }

  // epilogue 1: h1 = relu(acc + b1) -> wave-private LDS slice, bf16
  unsigned short* myH1 = sH1 + m0 * H1W;
  #pragma unroll
  for (int ni = 0; ni < NF1; ++ni) {
    const int col = ni * 16 + l15;
    const float b1v = E.b1[col];
    #pragma unroll
    for (int r = 0; r < 4; ++r)
      myH1[(quad * 4 + r) * H1W + col] = f2bf(fmaxf(acc[ni][r] + b1v, 0.f));
  }

  // stage W2T into the (dead) A/B double-buffer region
  {
    constexpr int CH = HN2 * HN / 8;     // v8s chunks
    #pragma unroll
    for (int i = 0; i < CH / 256; ++i) {
      const int c = i * 256 + t;
      const int nn = c / (HN / 8), kc = (c % (HN / 8)) * 8;
      *(v8s*)&sW2[nn * H1W + kc] = *(const v8s*)(E.w2t + nn * HN + kc);
    }
  }
  __syncthreads();   // publish sW2

  // layer 2: h2 = relu(h1 @ W2 + b2), K = HN; h2 stays in f32 registers
  v4f acc2[NF2];
  #pragma unroll
  for (int ni = 0; ni < NF2; ++ni) acc2[ni] = (v4f){0.f, 0.f, 0.f, 0.f};
  #pragma unroll
  for (int ks = 0; ks < HN / 32; ++ks) {
    v8s a2 = *(const v8s*)&myH1[l15 * H1W + ks * 32 + quad * 8];
    #pragma unroll
    for (int ni = 0; ni < NF2; ++ni) {
      v8s b2 = *(const v8s*)&sW2[(ni * 16 + l15) * H1W + ks * 32 + quad * 8];
      acc2[ni] = __builtin_amdgcn_mfma_f32_16x16x32_bf16(a2, b2, acc2[ni], 0, 0, 0);
    }
  }

  // layer 3: out = relu(h2) @ W3 + b3, in-register shuffle reduce over 16 lanes
  float w3v[NF2], b2v[NF2];
  #pragma unroll
  for (int ni = 0; ni < NF2; ++ni) {
    const int c = ni * 16 + l15;
    w3v[ni] = E.w3[c];
    b2v[ni] = E.b2[c];
  }
  const float b3v = E.b3[0];
  #pragma unroll
  for (int r = 0; r < 4; ++r) {
    float s = 0.f;
    #pragma unroll
    for (int ni = 0; ni < NF2; ++ni)
      s = fmaf(fmaxf(acc2[ni][r] + b2v[ni], 0.f), w3v[ni], s);
    s += __shfl_xor(s, 1);
    s += __shfl_xor(s, 2);
    s += __shfl_xor(s, 4);
    s += __shfl_xor(s, 8);
    if (l15 == 0) {
      const int row = m0 + quad * 4 + r;
      if (row < rv) out[E.idx[tile0 + row]] = s + b3v;
    }
  }
}

__global__ __launch_bounds__(256, 3)
void moe_main(const float* __restrict__ x, float* __restrict__ out, Quad q)
{
  // max LDS (HN=128): 48128 B -> 3 blocks/CU
  __shared__ __align__(16) char smem[48128];
  const int e = blockIdx.y;
  if (e < 2) moe_body<64>(x, out, q.e[e], smem);
  else       moe_body<128>(x, out, q.e[e], smem);
}

// ---------------- host ----------------
extern "C" void kernel_launch(void* const* d_in, const int* in_sizes, int n_in,
                              void* d_out, int out_size, void* d_ws, size_t ws_size,
                              hipStream_t stream)
{
  const float* x   = (const float*)d_in[0];
  const int* labels = (const int*)d_in[1];
  float* out = (float*)d_out;

  char* ws = (char*)d_ws;
  int* counts = (int*)ws;                       // 16 B
  int* idx = (int*)(ws + 256);                  // 4 * 65536 ints = 1 MiB
  static const int HNs[4] = {64, 64, 128, 128};
  unsigned short* w1t[4];
  unsigned short* w2t[4];
  size_t off = 256 + (size_t)4 * NROWS * 4;
  for (int e = 0; e < 4; ++e) { w1t[e] = (unsigned short*)(ws + off); off += (size_t)IDIM * HNs[e] * 2; }
  for (int e = 0; e < 4; ++e) { w2t[e] = (unsigned short*)(ws + off); off += (size_t)HNs[e] * (HNs[e] / 2) * 2; }

  hipMemsetAsync(counts, 0, 4 * sizeof(int), stream);
  build_lists<<<dim3(NROWS / 256), dim3(256), 0, stream>>>(labels, out, counts, idx, NROWS);

  ConvArgs ca;
  for (int e = 0; e < 4; ++e) {
    ca.W1[e] = (const float*)d_in[2 + 6 * e + 0];
    ca.W2[e] = (const float*)d_in[2 + 6 * e + 2];
    ca.w1t[e] = w1t[e];
    ca.w2t[e] = w2t[e];
    ca.HN[e] = HNs[e];
  }
  // max total = IDIM*128 + 128*64 = 270336 -> 1056 blocks of 256
  conv_all<<<dim3(1056, 4), dim3(256), 0, stream>>>(ca);

  Quad q;
  for (int e = 0; e < 4; ++e) {
    q.e[e].w1t = w1t[e];
    q.e[e].b1  = (const float*)d_in[2 + 6 * e + 1];
    q.e[e].w2t = w2t[e];
    q.e[e].b2  = (const float*)d_in[2 + 6 * e + 3];
    q.e[e].w3  = (const float*)d_in[2 + 6 * e + 4];
    q.e[e].b3  = (const float*)d_in[2 + 6 * e + 5];
    q.e[e].idx = idx + (size_t)e * NROWS;
    q.e[e].count = counts + e;
  }
  moe_main<<<dim3(NROWS / 64, 4), dim3(256), 0, stream>>>(x, out, q);
}